// Round 1
// baseline (674.950 us; speedup 1.0000x reference)
//
#include <hip/hip_runtime.h>
#include <math.h>

// LSTM: B=8192, T=512, IN=3, H=32, OUT=2, fp32.
// Strategy: thread (b, j) owns hidden unit j of batch b. Lane keeps its four
// W_hh rows (i,f,g,o) in VGPRs (128 regs, time-invariant); h is exchanged per
// timestep through a double-buffered LDS array. Block = 64 threads = 1 wave =
// 2 batch elements -> barrier is intra-wave (cheap). 4096 blocks.

namespace {
constexpr int kIn  = 3;
constexpr int kH   = 32;
constexpr int kT   = 512;
constexpr int kOut = 2;
} // namespace

__device__ __forceinline__ float fast_rcp(float v) { return __builtin_amdgcn_rcpf(v); }
__device__ __forceinline__ float sigmoid_f(float v) {
    // safe for any v: exp(-v) -> inf => rcp(inf)=0; exp(-v) -> 0 => 1
    return fast_rcp(1.0f + __expf(-v));
}
__device__ __forceinline__ float tanh_f(float v) {
    // overflow-safe: e in (0,1]
    float e = __expf(-2.0f * fabsf(v));
    float r = (1.0f - e) * fast_rcp(1.0f + e);
    return copysignf(r, v);
}

extern "C" __global__ __launch_bounds__(64, 2)
void lstm_fused(const float* __restrict__ x,
                const float* __restrict__ W_ih,
                const float* __restrict__ W_hh,
                const float* __restrict__ b_ih,
                const float* __restrict__ b_hh,
                const float* __restrict__ W_fc,
                const float* __restrict__ b_fc,
                float* __restrict__ out) {
    const int tid = threadIdx.x;
    const int jl  = tid & 31;   // hidden unit this lane owns
    const int bb  = tid >> 5;   // batch slot within block (0/1)
    const int b   = blockIdx.x * 2 + bb;

    __shared__ __align__(16) float hbuf[2][2][kH];  // [buffer][batch-slot][j]

    // PyTorch gate order rows: i=j, f=32+j, g=64+j, o=96+j
    const int ri = jl, rf = kH + jl, rg = 2 * kH + jl, ro = 3 * kH + jl;

    // Recurrent weights for this lane's four gates, held in VGPRs.
    float4 wi[8], wf[8], wg[8], wo[8];
#pragma unroll
    for (int q = 0; q < 8; ++q) {
        wi[q] = reinterpret_cast<const float4*>(W_hh + ri * kH)[q];
        wf[q] = reinterpret_cast<const float4*>(W_hh + rf * kH)[q];
        wg[q] = reinterpret_cast<const float4*>(W_hh + rg * kH)[q];
        wo[q] = reinterpret_cast<const float4*>(W_hh + ro * kH)[q];
    }
    const float wxi0 = W_ih[ri * kIn + 0], wxi1 = W_ih[ri * kIn + 1], wxi2 = W_ih[ri * kIn + 2];
    const float wxf0 = W_ih[rf * kIn + 0], wxf1 = W_ih[rf * kIn + 1], wxf2 = W_ih[rf * kIn + 2];
    const float wxg0 = W_ih[rg * kIn + 0], wxg1 = W_ih[rg * kIn + 1], wxg2 = W_ih[rg * kIn + 2];
    const float wxo0 = W_ih[ro * kIn + 0], wxo1 = W_ih[ro * kIn + 1], wxo2 = W_ih[ro * kIn + 2];
    const float pbi = b_ih[ri] + b_hh[ri];
    const float pbf = b_ih[rf] + b_hh[rf];
    const float pbg = b_ih[rg] + b_hh[rg];
    const float pbo = b_ih[ro] + b_hh[ro];

    float c = 0.0f, h = 0.0f;
    hbuf[0][bb][jl] = 0.0f;
    __syncthreads();

    const float* xp = x + (size_t)b * kT * kIn;
    int p = 0;
    for (int t = 0; t < kT; ++t) {
        const float x0 = xp[t * kIn + 0];
        const float x1 = xp[t * kIn + 1];
        const float x2 = xp[t * kIn + 2];
        float gi = fmaf(x0, wxi0, fmaf(x1, wxi1, fmaf(x2, wxi2, pbi)));
        float gf = fmaf(x0, wxf0, fmaf(x1, wxf1, fmaf(x2, wxf2, pbf)));
        float gg = fmaf(x0, wxg0, fmaf(x1, wxg1, fmaf(x2, wxg2, pbg)));
        float go = fmaf(x0, wxo0, fmaf(x1, wxo1, fmaf(x2, wxo2, pbo)));

        const float4* hv = reinterpret_cast<const float4*>(&hbuf[p][bb][0]);
#pragma unroll
        for (int q = 0; q < 8; ++q) {
            const float4 h4 = hv[q];
            gi = fmaf(h4.x, wi[q].x, gi);
            gi = fmaf(h4.y, wi[q].y, gi);
            gi = fmaf(h4.z, wi[q].z, gi);
            gi = fmaf(h4.w, wi[q].w, gi);
            gf = fmaf(h4.x, wf[q].x, gf);
            gf = fmaf(h4.y, wf[q].y, gf);
            gf = fmaf(h4.z, wf[q].z, gf);
            gf = fmaf(h4.w, wf[q].w, gf);
            gg = fmaf(h4.x, wg[q].x, gg);
            gg = fmaf(h4.y, wg[q].y, gg);
            gg = fmaf(h4.z, wg[q].z, gg);
            gg = fmaf(h4.w, wg[q].w, gg);
            go = fmaf(h4.x, wo[q].x, go);
            go = fmaf(h4.y, wo[q].y, go);
            go = fmaf(h4.z, wo[q].z, go);
            go = fmaf(h4.w, wo[q].w, go);
        }

        const float iv = sigmoid_f(gi);
        const float fv = sigmoid_f(gf);
        const float gv = tanh_f(gg);
        const float ov = sigmoid_f(go);
        c = fmaf(fv, c, iv * gv);
        h = ov * tanh_f(c);

        hbuf[p ^ 1][bb][jl] = h;
        __syncthreads();
        p ^= 1;
    }

    // fc: out[b, o] = sum_j h_j * W_fc[o, j] + b_fc[o]; reduce over 32 lanes.
    float s0 = h * W_fc[jl];
    float s1 = h * W_fc[kH + jl];
#pragma unroll
    for (int m = 16; m >= 1; m >>= 1) {
        s0 += __shfl_xor(s0, m, 32);
        s1 += __shfl_xor(s1, m, 32);
    }
    if (jl == 0) {
        out[(size_t)b * kOut + 0] = s0 + b_fc[0];
        out[(size_t)b * kOut + 1] = s1 + b_fc[1];
    }
}

extern "C" void kernel_launch(void* const* d_in, const int* in_sizes, int n_in,
                              void* d_out, int out_size, void* d_ws, size_t ws_size,
                              hipStream_t stream) {
    const float* x    = (const float*)d_in[0];
    const float* W_ih = (const float*)d_in[1];
    const float* W_hh = (const float*)d_in[2];
    const float* b_ih = (const float*)d_in[3];
    const float* b_hh = (const float*)d_in[4];
    const float* W_fc = (const float*)d_in[5];
    const float* b_fc = (const float*)d_in[6];
    float* out = (float*)d_out;

    const int batch = in_sizes[0] / (kT * kIn);  // 8192
    dim3 grid(batch / 2);
    dim3 block(64);
    hipLaunchKernelGGL(lstm_fused, grid, block, 0, stream,
                       x, W_ih, W_hh, b_ih, b_hh, W_fc, b_fc, out);
}